// Round 5
// baseline (265.383 us; speedup 1.0000x reference)
//
#include <hip/hip_runtime.h>

#define Bn 256
#define Tn 512
#define Cn 256
#define Kn 8

typedef __attribute__((ext_vector_type(4))) float f32x4;

// v6: v1's known-good occupancy geometry + v5's pressure-reduced compute core.
//
// History: v1 (512thr, 64KiB LDS, 2 blk/CU = 4 waves/SIMD, grid 512) ran
// ~68us WITH ~35-reg spill and per-strip A re-reads. v2-v5 (double-buffered,
// 2 t/block) all ran 80-96us: v2/v3 at a 64-arch-reg budget (spill 140B/thr),
// v4/v5 spill-reduced but only 2 waves/SIMD -> latency-bound (no pipe >17%).
// v5 proved spill reduction alone doesn't pay at 2 waves/SIMD; v1 proved
// 4 waves/SIMD pays even with spill. The 2-t/block overlap is arithmetically
// neutral (chip-wide staging is 21us either way), so drop it.
//
// v6 = v1 shell (one t/block, grid 512, single 64KiB fp8 buffer, ~69KB LDS
// -> 2 blocks/CU, 16 waves/CU) + v5 core:
//   - A-fragments resident per block (8 ds_read_b128, statically indexed),
//   - 32-col half-strips: acc[2][2] (16 AGPR), B in-flight 16 VGPR,
//   - total demand ~95 regs <= 128/wave budget at 4 waves/EU -> no spill.
//
// LDS tile layout: fp8 e4m3, paired-K swizzle — logical 8-byte half-unit
// b=kk*4+q (k-bytes [kk*32+q*8, +8)) stored at physical 16B unit
// u=(q*4+kp)^(row&7), half (kk&1): one ds_read_b128 feeds MFMAs kk=2kp,2kp+1.
__global__ __launch_bounds__(512)
__attribute__((amdgpu_waves_per_eu(4, 4)))
void tcon_k(const float* __restrict__ emb,
            const int* __restrict__ phon,
            const float* __restrict__ wts,
            float* __restrict__ out) {
    __shared__ __align__(16) unsigned char Esh[Bn * Bn];   // 64 KiB fp8
    __shared__ float invn[Bn];
    __shared__ int   pcls[Bn];
    __shared__ float num_s[Bn], den_s[Bn];
    __shared__ float csum[Kn];
    __shared__ int   ccnt[Kn];

    const int t    = blockIdx.x;
    const int tid  = threadIdx.x;
    const int lane = tid & 63;
    const int wave = tid >> 6;        // 0..7
    const int i0   = wave * 32;       // rows [i0, i0+32)

    const int q   = lane >> 4;
    const int l15 = lane & 15;
    const int e3  = l15 & 7;          // == row&7 for all our fragment rows

    if (tid < Kn) { csum[tid] = 0.0f; ccnt[tid] = 0; }
    if (tid < Bn) pcls[tid] = phon[tid * Tn + t];

    // ---- stage t into Esh (512 B fp32 -> 128 B fp8 per thread) ----
    #pragma unroll 4
    for (int it = 0; it < 16; ++it) {
        const int f   = tid + it * 512;
        const int row = f >> 5;
        const int b   = f & 31;                 // logical 8B half-unit
        const float4* p = (const float4*)(emb + ((size_t)row * Tn + t) * Cn);
        const float4 v0 = p[2 * b];
        const float4 v1 = p[2 * b + 1];
        int lo = __builtin_amdgcn_cvt_pk_fp8_f32(v0.x, v0.y, 0, false);
        lo     = __builtin_amdgcn_cvt_pk_fp8_f32(v0.z, v0.w, lo, true);
        int hi = __builtin_amdgcn_cvt_pk_fp8_f32(v1.x, v1.y, 0, false);
        hi     = __builtin_amdgcn_cvt_pk_fp8_f32(v1.z, v1.w, hi, true);
        const int qq = b & 3, kk = b >> 2, kp = kk >> 1;
        const int ad = row * 256 + ((((qq << 2) + kp) ^ (row & 7)) << 4)
                     + ((kk & 1) << 3);
        int2 pk; pk.x = lo; pk.y = hi;
        *(int2*)&Esh[ad] = pk;
    }
    __syncthreads();

    f32x4 acc[2][2];

// 32-col half-strip: B in-flight = 8 ulonglong2 max; A from resident a_[][].
#define COMPUTE_HALF(JB) do {                                                \
    _Pragma("unroll") for (int _m = 0; _m < 2; ++_m)                         \
    _Pragma("unroll") for (int _n = 0; _n < 2; ++_n)                         \
        acc[_m][_n] = (f32x4){0.f, 0.f, 0.f, 0.f};                           \
    _Pragma("unroll") for (int _kp = 0; _kp < 4; ++_kp) {                    \
        const int _sw = (((q << 2) + _kp) ^ e3) << 4;                        \
        ulonglong2 _b[2];                                                    \
        _Pragma("unroll") for (int _n = 0; _n < 2; ++_n)                     \
            _b[_n] = *(const ulonglong2*)&Esh[((JB) + _n * 16 + l15) * 256 + _sw]; \
        _Pragma("unroll") for (int _m = 0; _m < 2; ++_m)                     \
        _Pragma("unroll") for (int _n = 0; _n < 2; ++_n) {                   \
            acc[_m][_n] = __builtin_amdgcn_mfma_f32_16x16x32_fp8_fp8(        \
                (long)a_[_kp][_m].x, (long)_b[_n].x, acc[_m][_n], 0, 0, 0);  \
            acc[_m][_n] = __builtin_amdgcn_mfma_f32_16x16x32_fp8_fp8(        \
                (long)a_[_kp][_m].y, (long)_b[_n].y, acc[_m][_n], 0, 0, 0);  \
        }                                                                    \
    }                                                                        \
} while (0)

#define EPILOGUE(JB) do {                                                    \
    _Pragma("unroll") for (int _n = 0; _n < 2; ++_n) {                       \
        const int _j  = (JB) + _n * 16 + l15;                                \
        const int _pj = pcls[_j];                                            \
        const float _ij = invn[_j];                                          \
        _Pragma("unroll") for (int _m = 0; _m < 2; ++_m)                     \
        _Pragma("unroll") for (int _r = 0; _r < 4; ++_r) {                   \
            const int _e = _m * 4 + _r;                                      \
            const int _ir = i0 + _m * 16 + q * 4 + _r;                       \
            const float _ex = __expf(acc[_m][_n][_r] * inv_i[_e] * _ij);     \
            const bool _nd = (_ir != _j);                                    \
            den_p[_e] += _nd ? _ex : 0.0f;                                   \
            num_p[_e] += (_nd && (_pj == pi[_e])) ? _ex : 0.0f;              \
        }                                                                    \
    }                                                                        \
} while (0)

    // ---- A fragments resident (16 VGPRs, statically indexed) ----
    ulonglong2 a_[4][2];
    #pragma unroll
    for (int kp = 0; kp < 4; ++kp)
        #pragma unroll
        for (int m = 0; m < 2; ++m)
            a_[kp][m] = *(const ulonglong2*)
                &Esh[(i0 + m * 16 + l15) * 256 + ((((q << 2) + kp) ^ e3) << 4)];

    // ---- diagonal half-strip first; publish norms (uniform path) ----
    COMPUTE_HALF(i0);
    #pragma unroll
    for (int r = 0; r < 4; ++r)
        if (l15 == q * 4 + r) {
            invn[i0 + l15]      = rsqrtf(fmaxf(acc[0][0][r], 1e-24f));
            invn[i0 + 16 + l15] = rsqrtf(fmaxf(acc[1][1][r], 1e-24f));
        }
    __syncthreads();               // invn published

    float num_p[8], den_p[8], inv_i[8];
    int   pi[8];
    #pragma unroll
    for (int e = 0; e < 8; ++e) {
        const int irow = i0 + (e >> 2) * 16 + q * 4 + (e & 3);
        num_p[e] = 0.0f; den_p[e] = 0.0f;
        pi[e]    = pcls[irow];
        inv_i[e] = invn[irow];
    }

    EPILOGUE(i0);                  // consume held diagonal acc
    #pragma unroll
    for (int k = 1; k < 8; ++k) {  // remaining half-strips, permutation order
        const int jb = (wave ^ k) * 32;
        COMPUTE_HALF(jb);
        EPILOGUE(jb);
    }

    // Reduce across the 16 l15 lanes of each quad; each row owned by 1 wave.
    #pragma unroll
    for (int e = 0; e < 8; ++e) {
        float n = num_p[e], d = den_p[e];
        #pragma unroll
        for (int m = 1; m <= 8; m <<= 1) {
            n += __shfl_xor(n, m, 64);
            d += __shfl_xor(d, m, 64);
        }
        if (l15 == e) {
            const int irow = i0 + (e >> 2) * 16 + q * 4 + (e & 3);
            num_s[irow] = n;
            den_s[irow] = d;
        }
    }
    __syncthreads();

    // ---- per-sample loss, class means, weighted mean ----
    if (tid < Bn) {
        const float ps = __logf(den_s[tid] + 1e-6f) - __logf(num_s[tid]);
        atomicAdd(&csum[pcls[tid]], ps);
        atomicAdd(&ccnt[pcls[tid]], 1);
    }
    __syncthreads();

    if (tid == 0) {
        float accv = 0.0f; int np = 0;
        #pragma unroll
        for (int k = 0; k < Kn; ++k)
            if (ccnt[k] > 0) { accv += (csum[k] / (float)ccnt[k]) * wts[k]; ++np; }
        atomicAdd(out, (accv / (float)np) * (1.0f / (float)Tn));
    }
#undef COMPUTE_HALF
#undef EPILOGUE
}

extern "C" void kernel_launch(void* const* d_in, const int* in_sizes, int n_in,
                              void* d_out, int out_size, void* d_ws, size_t ws_size,
                              hipStream_t stream) {
    const float* emb  = (const float*)d_in[0];
    const int*   phon = (const int*)d_in[1];
    const float* wts  = (const float*)d_in[2];
    float*       out  = (float*)d_out;

    hipMemsetAsync(out, 0, sizeof(float), stream);
    tcon_k<<<Tn, 512, 0, stream>>>(emb, phon, wts, out);
}

// Round 6
// 207.334 us; speedup vs baseline: 1.2800x; 1.2800x over previous
//
#include <hip/hip_runtime.h>

#define Bn 256
#define Tn 512
#define Cn 256
#define Kn 8

typedef __attribute__((ext_vector_type(4))) float f32x4;

// v7 = v1 shell (proven best: grid 512, 512 thr, single 64 KiB fp8 buffer,
// 2 blocks/CU, 4 waves/SIMD, __launch_bounds__(512,4), no waves_per_eu attr)
// with ONLY the compute core's transient register pressure reduced:
//   - 32-col half-strips: acc[2][2] (16 acc regs), B in-flight 8x16B,
//   - A fragments RE-READ per half-strip (transient, nothing pinned).
// Peak arch-VGPR demand ~76 (vs v1's ~127) -> minimal spill even at the
// compiler's habitual 64-arch-reg split.
//
// v6 post-mortem (the 137us disaster): pinning a_[4][2] resident across the
// kernel at a 64-arch-reg allocation forced ~630 B/thread scratch
// (WRITE_SIZE 166 MB). The pin was the poison — removed here.
//
// LDS tile layout (unchanged): fp8 e4m3, paired-K swizzle — logical 8-byte
// half-unit b=kk*4+q (k-bytes [kk*32+q*8, +8)) stored at physical 16B unit
// u=(q*4+kp)^(row&7), half (kk&1): one ds_read_b128 feeds MFMAs kk=2kp,2kp+1.
__global__ __launch_bounds__(512, 4)
void tcon_k(const float* __restrict__ emb,
            const int* __restrict__ phon,
            const float* __restrict__ wts,
            float* __restrict__ out) {
    __shared__ __align__(16) unsigned char Esh[Bn * Bn];   // 64 KiB fp8
    __shared__ float invn[Bn];
    __shared__ int   pcls[Bn];
    __shared__ float num_s[Bn], den_s[Bn];
    __shared__ float csum[Kn];
    __shared__ int   ccnt[Kn];

    const int t    = blockIdx.x;
    const int tid  = threadIdx.x;
    const int lane = tid & 63;
    const int wave = tid >> 6;        // 0..7
    const int i0   = wave * 32;       // rows [i0, i0+32)

    const int q   = lane >> 4;
    const int l15 = lane & 15;
    const int e3  = l15 & 7;          // == row&7 for all our fragment rows

    if (tid < Kn) { csum[tid] = 0.0f; ccnt[tid] = 0; }
    if (tid < Bn) pcls[tid] = phon[tid * Tn + t];

    // ---- Phase 1: stream fp32 -> fp8 e4m3 into paired-K swizzled LDS ----
    #pragma unroll 4
    for (int it = 0; it < 16; ++it) {
        const int f   = tid + it * 512;
        const int row = f >> 5;
        const int b   = f & 31;                 // logical 8B half-unit
        const float4* p = (const float4*)(emb + ((size_t)row * Tn + t) * Cn);
        const float4 v0 = p[2 * b];
        const float4 v1 = p[2 * b + 1];
        int lo = __builtin_amdgcn_cvt_pk_fp8_f32(v0.x, v0.y, 0, false);
        lo     = __builtin_amdgcn_cvt_pk_fp8_f32(v0.z, v0.w, lo, true);
        int hi = __builtin_amdgcn_cvt_pk_fp8_f32(v1.x, v1.y, 0, false);
        hi     = __builtin_amdgcn_cvt_pk_fp8_f32(v1.z, v1.w, hi, true);
        const int qq = b & 3, kk = b >> 2, kp = kk >> 1;
        const int ad = row * 256 + ((((qq << 2) + kp) ^ (row & 7)) << 4)
                     + ((kk & 1) << 3);
        int2 pk; pk.x = lo; pk.y = hi;
        *(int2*)&Esh[ad] = pk;
    }
    __syncthreads();

    f32x4 acc[2][2];

// 32-col half-strip. A and B fragments both read transiently from LDS
// (8 + 8 ds_read_b128 in flight max = 32 VGPRs); acc[2][2] in acc regs.
#define COMPUTE_HALF(JB) do {                                                \
    _Pragma("unroll") for (int _m = 0; _m < 2; ++_m)                         \
    _Pragma("unroll") for (int _n = 0; _n < 2; ++_n)                         \
        acc[_m][_n] = (f32x4){0.f, 0.f, 0.f, 0.f};                           \
    _Pragma("unroll") for (int _kp = 0; _kp < 4; ++_kp) {                    \
        const int _sw = (((q << 2) + _kp) ^ e3) << 4;                        \
        ulonglong2 _a[2], _b[2];                                             \
        _Pragma("unroll") for (int _m = 0; _m < 2; ++_m)                     \
            _a[_m] = *(const ulonglong2*)&Esh[(i0 + _m * 16 + l15) * 256 + _sw]; \
        _Pragma("unroll") for (int _n = 0; _n < 2; ++_n)                     \
            _b[_n] = *(const ulonglong2*)&Esh[((JB) + _n * 16 + l15) * 256 + _sw]; \
        _Pragma("unroll") for (int _m = 0; _m < 2; ++_m)                     \
        _Pragma("unroll") for (int _n = 0; _n < 2; ++_n) {                   \
            acc[_m][_n] = __builtin_amdgcn_mfma_f32_16x16x32_fp8_fp8(        \
                (long)_a[_m].x, (long)_b[_n].x, acc[_m][_n], 0, 0, 0);       \
            acc[_m][_n] = __builtin_amdgcn_mfma_f32_16x16x32_fp8_fp8(        \
                (long)_a[_m].y, (long)_b[_n].y, acc[_m][_n], 0, 0, 0);       \
        }                                                                    \
    }                                                                        \
} while (0)

#define EPILOGUE(JB) do {                                                    \
    _Pragma("unroll") for (int _n = 0; _n < 2; ++_n) {                       \
        const int _j  = (JB) + _n * 16 + l15;                                \
        const int _pj = pcls[_j];                                            \
        const float _ij = invn[_j];                                          \
        _Pragma("unroll") for (int _m = 0; _m < 2; ++_m)                     \
        _Pragma("unroll") for (int _r = 0; _r < 4; ++_r) {                   \
            const int _e = _m * 4 + _r;                                      \
            const int _ir = i0 + _m * 16 + q * 4 + _r;                       \
            const float _ex = __expf(acc[_m][_n][_r] * inv_i[_e] * _ij);     \
            const bool _nd = (_ir != _j);                                    \
            den_p[_e] += _nd ? _ex : 0.0f;                                   \
            num_p[_e] += (_nd && (_pj == pi[_e])) ? _ex : 0.0f;              \
        }                                                                    \
    }                                                                        \
} while (0)

    // ---- diagonal half-strip first; publish norms (uniform path) ----
    COMPUTE_HALF(i0);
    #pragma unroll
    for (int r = 0; r < 4; ++r)
        if (l15 == q * 4 + r) {
            invn[i0 + l15]      = rsqrtf(fmaxf(acc[0][0][r], 1e-24f));
            invn[i0 + 16 + l15] = rsqrtf(fmaxf(acc[1][1][r], 1e-24f));
        }
    __syncthreads();               // all norms published

    float num_p[8], den_p[8], inv_i[8];
    int   pi[8];
    #pragma unroll
    for (int e = 0; e < 8; ++e) {
        const int irow = i0 + (e >> 2) * 16 + q * 4 + (e & 3);
        num_p[e] = 0.0f; den_p[e] = 0.0f;
        pi[e]    = pcls[irow];
        inv_i[e] = invn[irow];
    }

    EPILOGUE(i0);                  // consume held diagonal acc
    for (int k = 1; k < 8; ++k) {  // remaining half-strips (wave-uniform)
        const int jb = (wave ^ k) * 32;
        COMPUTE_HALF(jb);
        EPILOGUE(jb);
    }

    // Reduce across the 16 l15 lanes of each quad; each row owned by 1 wave.
    #pragma unroll
    for (int e = 0; e < 8; ++e) {
        float n = num_p[e], d = den_p[e];
        #pragma unroll
        for (int m = 1; m <= 8; m <<= 1) {
            n += __shfl_xor(n, m, 64);
            d += __shfl_xor(d, m, 64);
        }
        if (l15 == e) {
            const int irow = i0 + (e >> 2) * 16 + q * 4 + (e & 3);
            num_s[irow] = n;
            den_s[irow] = d;
        }
    }
    __syncthreads();

    // ---- Phase 3: per-sample loss, class means, weighted mean ----
    if (tid < Bn) {
        const float ps = __logf(den_s[tid] + 1e-6f) - __logf(num_s[tid]);
        atomicAdd(&csum[pcls[tid]], ps);
        atomicAdd(&ccnt[pcls[tid]], 1);
    }
    __syncthreads();

    if (tid == 0) {
        float accv = 0.0f; int np = 0;
        #pragma unroll
        for (int k = 0; k < Kn; ++k)
            if (ccnt[k] > 0) { accv += (csum[k] / (float)ccnt[k]) * wts[k]; ++np; }
        atomicAdd(out, (accv / (float)np) * (1.0f / (float)Tn));
    }
#undef COMPUTE_HALF
#undef EPILOGUE
}

extern "C" void kernel_launch(void* const* d_in, const int* in_sizes, int n_in,
                              void* d_out, int out_size, void* d_ws, size_t ws_size,
                              hipStream_t stream) {
    const float* emb  = (const float*)d_in[0];
    const int*   phon = (const int*)d_in[1];
    const float* wts  = (const float*)d_in[2];
    float*       out  = (float*)d_out;

    hipMemsetAsync(out, 0, sizeof(float), stream);
    tcon_k<<<Tn, 512, 0, stream>>>(emb, phon, wts, out);
}